// Round 1
// baseline (42.721 us; speedup 1.0000x reference)
//
#include <hip/hip_runtime.h>

#define BATCH 16384
#define FEAT 2048
#define ROWS_PER_BLOCK 4   // 4 waves of 64 lanes per 256-thread block

// Kernel 1: one wave per row. dist[b] = ||x_b||^2 + ||c_lb||^2 - 2 x_b.c_lb,
// clipped to [1e-12, 1e12]. One partial sum (over 4 rows) per block -> ws.
__global__ __launch_bounds__(256) void center_loss_rows(
    const float* __restrict__ x, const int* __restrict__ labels,
    const float* __restrict__ centers, float* __restrict__ partials)
{
    const int wave = threadIdx.x >> 6;   // 0..3
    const int lane = threadIdx.x & 63;
    const int row  = blockIdx.x * ROWS_PER_BLOCK + wave;  // grid covers BATCH exactly

    const float4* __restrict__ xr =
        reinterpret_cast<const float4*>(x + (size_t)row * FEAT);
    const int lbl = labels[row];
    const float4* __restrict__ cr =
        reinterpret_cast<const float4*>(centers + (size_t)lbl * FEAT);

    float sxx = 0.f, sxc = 0.f, scc = 0.f;
#pragma unroll
    for (int j = 0; j < FEAT / 4 / 64; ++j) {   // 8 iterations
        const float4 xv = xr[lane + 64 * j];
        const float4 cv = cr[lane + 64 * j];
        sxx += xv.x * xv.x + xv.y * xv.y + xv.z * xv.z + xv.w * xv.w;
        sxc += xv.x * cv.x + xv.y * cv.y + xv.z * cv.z + xv.w * cv.w;
        scc += cv.x * cv.x + cv.y * cv.y + cv.z * cv.z + cv.w * cv.w;
    }

    // 64-lane wave reduction (wave64 on CDNA)
#pragma unroll
    for (int off = 32; off; off >>= 1) {
        sxx += __shfl_down(sxx, off, 64);
        sxc += __shfl_down(sxc, off, 64);
        scc += __shfl_down(scc, off, 64);
    }

    __shared__ float sdist[ROWS_PER_BLOCK];
    if (lane == 0) {
        float d = sxx + scc - 2.0f * sxc;
        d = fminf(fmaxf(d, 1e-12f), 1e12f);   // reference clip
        sdist[wave] = d;
    }
    __syncthreads();
    if (threadIdx.x == 0) {
        partials[blockIdx.x] = sdist[0] + sdist[1] + sdist[2] + sdist[3];
    }
}

// Kernel 2: deterministic tree reduction of the block partials -> mean.
__global__ __launch_bounds__(256) void reduce_partials(
    const float* __restrict__ partials, float* __restrict__ out, int n)
{
    float s = 0.f;
    for (int i = threadIdx.x; i < n; i += 256) s += partials[i];
    __shared__ float sm[256];
    sm[threadIdx.x] = s;
    __syncthreads();
#pragma unroll
    for (int off = 128; off; off >>= 1) {
        if (threadIdx.x < off) sm[threadIdx.x] += sm[threadIdx.x + off];
        __syncthreads();
    }
    if (threadIdx.x == 0) out[0] = sm[0] / (float)BATCH;
}

extern "C" void kernel_launch(void* const* d_in, const int* in_sizes, int n_in,
                              void* d_out, int out_size, void* d_ws, size_t ws_size,
                              hipStream_t stream) {
    const float* x       = (const float*)d_in[0];   // [BATCH, FEAT] f32
    const int*   labels  = (const int*)d_in[1];     // [BATCH] int
    const float* centers = (const float*)d_in[2];   // [NUM_CLASSES, FEAT] f32
    float* out = (float*)d_out;
    float* partials = (float*)d_ws;                 // 4096 floats

    const int nblocks = BATCH / ROWS_PER_BLOCK;     // 4096
    center_loss_rows<<<nblocks, 256, 0, stream>>>(x, labels, centers, partials);
    reduce_partials<<<1, 256, 0, stream>>>(partials, out, nblocks);
}